// Round 5
// baseline (43.774 us; speedup 1.0000x reference)
//
#include <hip/hip_runtime.h>
#include <math.h>

// Problem constants (match reference)
#define BB 8
#define NN 4096
#define LATENT 256

#define THREADS 256
#define P 8                           // query PAIRS per thread (16 queries)
#define CSPLIT 64                     // candidate tiles
#define TT (NN / CSPLIT)              // 64 candidates per tile
#define NSLOTS (2 * BB * NN)          // 65536 query slots
#define BLOCKS_X (2 * BB)             // 16 (dir x batch); each block does all 4096 queries

// Order-preserving float<->uint encoding (monotone)
__device__ __forceinline__ unsigned enc(float f) {
    unsigned b = __float_as_uint(f);
    return (b & 0x80000000u) ? ~b : (b | 0x80000000u);
}
__device__ __forceinline__ float dec(unsigned k) {
    unsigned b = (k & 0x80000000u) ? (k ^ 0x80000000u) : ~k;
    return __uint_as_float(b);
}

__device__ __forceinline__ float min3f(float a, float b, float c) {
    float d;
    asm("v_min3_f32 %0, %1, %2, %3" : "=v"(d) : "v"(a), "v"(b), "v"(c));
    return d;
}

// t(lo,hi) = cand-component broadcast * query-pair, accumulated:
//   t = (z,z)*qz + (w,w) ; t += (y,y)*qy ; t += (x,x)*qx
// cand stored as {-2x,-2y,-2z,|y|^2}: t = |y|^2 - 2*dot  for two queries at once.
__device__ __forceinline__ float2 dist_pk(float2 cxy, float2 czw,
                                          float2 qx, float2 qy, float2 qz) {
    float2 t;
    asm("v_pk_fma_f32 %0, %1, %2, %1 op_sel:[0,0,1] op_sel_hi:[0,1,1]"
        : "=v"(t) : "v"(czw), "v"(qz));                  // (z,z)*qz + (w,w)
    asm("v_pk_fma_f32 %0, %1, %2, %0 op_sel:[1,0,0] op_sel_hi:[1,1,1]"
        : "+v"(t) : "v"(cxy), "v"(qy));                  // += (y,y)*qy
    asm("v_pk_fma_f32 %0, %1, %2, %0 op_sel:[0,0,0] op_sel_hi:[0,1,1]"
        : "+v"(t) : "v"(cxy), "v"(qx));                  // += (x,x)*qx
    return t;
}

// ---------------------------------------------------------------------------
// Init: minkeys = +inf (encoded 0xFFFFFFFF), counter = 0. Replaces the
// pathologically slow runtime fill (measured ~40 us for 256 KB).
// ---------------------------------------------------------------------------
__global__ __launch_bounds__(THREADS)
void init_kernel(unsigned* __restrict__ minkeys, unsigned* __restrict__ counter)
{
    int i = blockIdx.x * THREADS + threadIdx.x;
    minkeys[i] = 0xFFFFFFFFu;
    if (i == 0) *counter = 0u;
}

// ---------------------------------------------------------------------------
// Stage 1: block (bx, c): bx = dir*8+b handles all 4096 queries (16/thread as
// 8 float2 pairs); c selects a 64-candidate tile staged in LDS (broadcast
// reads). Inner step: 2 candidates x 8 query-pairs, 6 v_pk_fma_f32 +
// 2 v_min3_f32 per 4 pairs = 2.0 VALU/pair. Tile-min -> atomicMin (encoded).
// ---------------------------------------------------------------------------
__global__ __launch_bounds__(THREADS, 4)
void chamfer_stage1(const float* __restrict__ recon,
                    const float* __restrict__ x,
                    unsigned* __restrict__ minkeys)
{
    __shared__ float4 ly[TT];        // 1 KB

    const int bx  = blockIdx.x;      // 0..15
    const int c   = blockIdx.y;      // 0..63
    const int dir = bx >> 3;
    const int b   = bx & 7;
    const int tid = threadIdx.x;

    const float* cloud = (dir ? recon : x) + (size_t)b * 3 * NN;
    const float* query = (dir ? x : recon) + (size_t)b * 3 * NN;

    if (tid < TT) {
        int m = c * TT + tid;
        float y0 = cloud[m];
        float y1 = cloud[NN + m];
        float y2 = cloud[2 * NN + m];
        ly[tid] = make_float4(-2.0f * y0, -2.0f * y1, -2.0f * y2,
                              y0 * y0 + y1 * y1 + y2 * y2);
    }
    __syncthreads();

    float2 qx[P], qy[P], qz[P];
    float mn0[P], mn1[P];
#pragma unroll
    for (int p = 0; p < P; ++p) {
        int ql = p * THREADS + tid;        // 0..2047
        int qh = ql + 2048;                // 2048..4095
        qx[p] = make_float2(query[ql],          query[qh]);
        qy[p] = make_float2(query[NN + ql],     query[NN + qh]);
        qz[p] = make_float2(query[2 * NN + ql], query[2 * NN + qh]);
        mn0[p] = 3.4e38f;
        mn1[p] = 3.4e38f;
    }

#pragma unroll 4
    for (int j = 0; j < TT; j += 2) {
        float4 A = ly[j];
        float4 B = ly[j + 1];
        float2 Axy = make_float2(A.x, A.y), Azw = make_float2(A.z, A.w);
        float2 Bxy = make_float2(B.x, B.y), Bzw = make_float2(B.z, B.w);
#pragma unroll
        for (int p = 0; p < P; ++p) {
            float2 ta = dist_pk(Axy, Azw, qx[p], qy[p], qz[p]);
            float2 tb = dist_pk(Bxy, Bzw, qx[p], qy[p], qz[p]);
            mn0[p] = min3f(mn0[p], ta.x, tb.x);
            mn1[p] = min3f(mn1[p], ta.y, tb.y);
        }
    }

    const int base = dir * (BB * NN) + b * NN;
#pragma unroll
    for (int p = 0; p < P; ++p) {
        int ql = p * THREADS + tid;
        int qh = ql + 2048;
        float sx0 = fmaf(qx[p].x, qx[p].x, fmaf(qy[p].x, qy[p].x, qz[p].x * qz[p].x));
        float sx1 = fmaf(qx[p].y, qx[p].y, fmaf(qy[p].y, qy[p].y, qz[p].y * qz[p].y));
        atomicMin(&minkeys[base + ql], enc(sx0 + mn0[p]));
        atomicMin(&minkeys[base + qh], enc(sx1 + mn1[p]));
    }
}

// ---------------------------------------------------------------------------
// Stage 2 + finalize (last-block pattern): decode per-query mins, block-sum;
// last block sums 256 totals, adds KL, writes 3 outputs.
// ---------------------------------------------------------------------------
__global__ __launch_bounds__(THREADS)
void chamfer_stage2(const unsigned* __restrict__ minkeys,
                    const float* __restrict__ mu,
                    const float* __restrict__ logvar,
                    float* __restrict__ sums,
                    unsigned* __restrict__ counter,
                    float* __restrict__ out)
{
    __shared__ float red[4];
    __shared__ float redA[4];
    __shared__ float redB[4];
    __shared__ int amLast;

    const int tid = threadIdx.x;
    const int bid = blockIdx.x;

    float v = dec(minkeys[bid * THREADS + tid]);
    for (int off = 32; off > 0; off >>= 1)
        v += __shfl_down(v, off);
    if ((tid & 63) == 0) red[tid >> 6] = v;
    __syncthreads();

    if (tid == 0) {
        float tot = red[0] + red[1] + red[2] + red[3];
        __hip_atomic_store(&sums[bid], tot, __ATOMIC_RELEASE, __HIP_MEMORY_SCOPE_AGENT);
        unsigned old = __hip_atomic_fetch_add(counter, 1u, __ATOMIC_ACQ_REL, __HIP_MEMORY_SCOPE_AGENT);
        amLast = (old == 255u);
    }
    __syncthreads();
    if (!amLast) return;

    float s = __hip_atomic_load(&sums[tid], __ATOMIC_ACQUIRE, __HIP_MEMORY_SCOPE_AGENT);

    float kl = 0.0f;
    for (int i = tid; i < BB * LATENT; i += THREADS) {
        float m  = mu[i];
        float lv = logvar[i];
        kl += 1.0f + lv - m * m - expf(lv);
    }

    for (int off = 32; off > 0; off >>= 1) {
        s  += __shfl_down(s, off);
        kl += __shfl_down(kl, off);
    }
    if ((tid & 63) == 0) { redA[tid >> 6] = s; redB[tid >> 6] = kl; }
    __syncthreads();
    if (tid == 0) {
        float recon = (redA[0] + redA[1] + redA[2] + redA[3]) / (float)(BB * NN);
        float kld   = -0.5f * (redB[0] + redB[1] + redB[2] + redB[3]) / (float)BB;
        out[0] = recon + kld;   // BETA = 1
        out[1] = recon;
        out[2] = kld;
    }
}

extern "C" void kernel_launch(void* const* d_in, const int* in_sizes, int n_in,
                              void* d_out, int out_size, void* d_ws, size_t ws_size,
                              hipStream_t stream)
{
    const float* recon  = (const float*)d_in[0];
    const float* x      = (const float*)d_in[1];
    const float* mu     = (const float*)d_in[2];
    const float* logvar = (const float*)d_in[3];
    float* out = (float*)d_out;

    unsigned* minkeys = (unsigned*)d_ws;             // 65536 uints (256 KB)
    float*    sums    = (float*)(minkeys + NSLOTS);  // 256 floats
    unsigned* counter = (unsigned*)(sums + 256);     // 1 uint

    init_kernel<<<NSLOTS / THREADS, THREADS, 0, stream>>>(minkeys, counter);

    dim3 g1(BLOCKS_X, CSPLIT);
    chamfer_stage1<<<g1, THREADS, 0, stream>>>(recon, x, minkeys);

    chamfer_stage2<<<NSLOTS / THREADS, THREADS, 0, stream>>>(minkeys, mu, logvar,
                                                             sums, counter, out);
}

// Round 6
// 39.503 us; speedup vs baseline: 1.1081x; 1.1081x over previous
//
#include <hip/hip_runtime.h>
#include <math.h>

// Problem constants (match reference)
#define BB 8
#define NN 4096
#define LATENT 256

#define THREADS 256
#define QP 4                          // query float2-PAIRS per thread (8 queries)
#define QBLK (THREADS * QP * 2)       // 2048 queries per block
#define QTILES (NN / QBLK)            // 2
#define CSPLIT 32                     // candidate tiles
#define TT (NN / CSPLIT)              // 128 candidates per tile
#define NSLOTS (2 * BB * NN)          // 65536 query slots
#define BLOCKS_X (2 * BB * QTILES)    // 32 (dir x batch x qtile)

__device__ __forceinline__ float min3f(float a, float b, float c) {
    float d;
    asm("v_min3_f32 %0, %1, %2, %3" : "=v"(d) : "v"(a), "v"(b), "v"(c));
    return d;
}

// Packed distance for 2 queries at once. cand stored {-2x,-2y,-2z,|y|^2}:
//   t = (z,z)*qz + (w,w); t += (y,y)*qy; t += (x,x)*qx  ->  |y|^2 - 2*dot
// (numerics validated in R5: absmax 0.0)
__device__ __forceinline__ float2 dist_pk(float2 cxy, float2 czw,
                                          float2 qx, float2 qy, float2 qz) {
    float2 t;
    asm("v_pk_fma_f32 %0, %1, %2, %1 op_sel:[0,0,1] op_sel_hi:[0,1,1]"
        : "=v"(t) : "v"(czw), "v"(qz));                  // (z,z)*qz + (w,w)
    asm("v_pk_fma_f32 %0, %1, %2, %0 op_sel:[1,0,0] op_sel_hi:[1,1,1]"
        : "+v"(t) : "v"(cxy), "v"(qy));                  // += (y,y)*qy
    asm("v_pk_fma_f32 %0, %1, %2, %0 op_sel:[0,0,0] op_sel_hi:[0,1,1]"
        : "+v"(t) : "v"(cxy), "v"(qx));                  // += (x,x)*qx
    return t;
}

// ---------------------------------------------------------------------------
// Stage 1: block (bx, c) = (dir,b,qtile) x candidate-tile c. Stages TT=128
// candidates into LDS as {-2y0,-2y1,-2y2,|y|^2}; each thread scans the tile
// for 8 queries held as 4 float2 pairs. Inner step (2 cands x 4 qpairs):
// 24 v_pk_fma_f32 + 8 v_min3_f32 = 2.0 VALU/pair. Plain coalesced stores of
// tile-mins to partial[c][slot] (deterministic, no atomics, no init).
// Also resets the stage-2 completion counter (block 0 only).
// ---------------------------------------------------------------------------
__global__ __launch_bounds__(THREADS, 4)
void chamfer_stage1(const float* __restrict__ recon,
                    const float* __restrict__ x,
                    float* __restrict__ partial,
                    unsigned* __restrict__ counter)
{
    __shared__ float4 ly[TT];        // 2 KB

    const int bx  = blockIdx.x;      // 0..31
    const int c   = blockIdx.y;      // 0..31
    const int dir = bx >> 4;
    const int rem = bx & 15;
    const int b   = rem >> 1;
    const int qt  = rem & 1;
    const int tid = threadIdx.x;

    if (bx == 0 && c == 0 && tid == 0) *counter = 0u;   // visible to stage2 (kernel boundary)

    const float* cloud = (dir ? recon : x) + (size_t)b * 3 * NN;
    const float* query = (dir ? x : recon) + (size_t)b * 3 * NN;

    for (int i = tid; i < TT; i += THREADS) {
        int m = c * TT + i;
        float y0 = cloud[m];
        float y1 = cloud[NN + m];
        float y2 = cloud[2 * NN + m];
        ly[i] = make_float4(-2.0f * y0, -2.0f * y1, -2.0f * y2,
                            y0 * y0 + y1 * y1 + y2 * y2);
    }
    __syncthreads();

    // 8 queries per thread: pairs (ql, qh) with qh = ql + QBLK/2
    const int q0 = qt * QBLK + tid;
    float2 qx[QP], qy[QP], qz[QP];
    float mn0[QP], mn1[QP];
#pragma unroll
    for (int p = 0; p < QP; ++p) {
        int ql = q0 + p * THREADS;
        int qh = ql + (QBLK / 2);
        qx[p] = make_float2(query[ql],          query[qh]);
        qy[p] = make_float2(query[NN + ql],     query[NN + qh]);
        qz[p] = make_float2(query[2 * NN + ql], query[2 * NN + qh]);
        mn0[p] = 3.4e38f;
        mn1[p] = 3.4e38f;
    }

#pragma unroll 2
    for (int j = 0; j < TT; j += 2) {
        float4 A = ly[j];
        float4 B = ly[j + 1];
        float2 Axy = make_float2(A.x, A.y), Azw = make_float2(A.z, A.w);
        float2 Bxy = make_float2(B.x, B.y), Bzw = make_float2(B.z, B.w);
#pragma unroll
        for (int p = 0; p < QP; ++p) {
            float2 ta = dist_pk(Axy, Azw, qx[p], qy[p], qz[p]);
            float2 tb = dist_pk(Bxy, Bzw, qx[p], qy[p], qz[p]);
            mn0[p] = min3f(mn0[p], ta.x, tb.x);
            mn1[p] = min3f(mn1[p], ta.y, tb.y);
        }
    }

    float* dst = partial + (size_t)c * NSLOTS + dir * (BB * NN) + b * NN;
#pragma unroll
    for (int p = 0; p < QP; ++p) {
        int ql = q0 + p * THREADS;
        int qh = ql + (QBLK / 2);
        float sx0 = fmaf(qx[p].x, qx[p].x, fmaf(qy[p].x, qy[p].x, qz[p].x * qz[p].x));
        float sx1 = fmaf(qx[p].y, qx[p].y, fmaf(qy[p].y, qy[p].y, qz[p].y * qz[p].y));
        dst[ql] = sx0 + mn0[p];
        dst[qh] = sx1 + mn1[p];
    }
}

// ---------------------------------------------------------------------------
// Stage 2 + finalize (last-block pattern, validated R4/R5): cross-tile min
// per query, block-sum; last block sums 256 totals, adds KL, writes 3 outputs.
// ---------------------------------------------------------------------------
__global__ __launch_bounds__(THREADS)
void chamfer_stage2(const float* __restrict__ partial,
                    const float* __restrict__ mu,
                    const float* __restrict__ logvar,
                    float* __restrict__ sums,
                    unsigned* __restrict__ counter,
                    float* __restrict__ out)
{
    __shared__ float red[4];
    __shared__ float redA[4];
    __shared__ float redB[4];
    __shared__ int amLast;

    const int tid = threadIdx.x;
    const int bid = blockIdx.x;
    const int gq  = bid * THREADS + tid;

    float m0 = partial[gq];
    float m1 = partial[(size_t)1 * NSLOTS + gq];
    for (int cc = 2; cc < CSPLIT; cc += 2) {
        float a = partial[(size_t)cc * NSLOTS + gq];
        float b = partial[(size_t)(cc + 1) * NSLOTS + gq];
        m0 = fminf(m0, a);
        m1 = fminf(m1, b);
    }
    float v = fminf(m0, m1);

    for (int off = 32; off > 0; off >>= 1)
        v += __shfl_down(v, off);
    if ((tid & 63) == 0) red[tid >> 6] = v;
    __syncthreads();

    if (tid == 0) {
        float tot = red[0] + red[1] + red[2] + red[3];
        __hip_atomic_store(&sums[bid], tot, __ATOMIC_RELEASE, __HIP_MEMORY_SCOPE_AGENT);
        unsigned old = __hip_atomic_fetch_add(counter, 1u, __ATOMIC_ACQ_REL, __HIP_MEMORY_SCOPE_AGENT);
        amLast = (old == 255u);
    }
    __syncthreads();
    if (!amLast) return;

    float s = __hip_atomic_load(&sums[tid], __ATOMIC_ACQUIRE, __HIP_MEMORY_SCOPE_AGENT);

    float kl = 0.0f;
    for (int i = tid; i < BB * LATENT; i += THREADS) {
        float m  = mu[i];
        float lv = logvar[i];
        kl += 1.0f + lv - m * m - expf(lv);
    }

    for (int off = 32; off > 0; off >>= 1) {
        s  += __shfl_down(s, off);
        kl += __shfl_down(kl, off);
    }
    if ((tid & 63) == 0) { redA[tid >> 6] = s; redB[tid >> 6] = kl; }
    __syncthreads();
    if (tid == 0) {
        float recon = (redA[0] + redA[1] + redA[2] + redA[3]) / (float)(BB * NN);
        float kld   = -0.5f * (redB[0] + redB[1] + redB[2] + redB[3]) / (float)BB;
        out[0] = recon + kld;   // BETA = 1
        out[1] = recon;
        out[2] = kld;
    }
}

extern "C" void kernel_launch(void* const* d_in, const int* in_sizes, int n_in,
                              void* d_out, int out_size, void* d_ws, size_t ws_size,
                              hipStream_t stream)
{
    const float* recon  = (const float*)d_in[0];
    const float* x      = (const float*)d_in[1];
    const float* mu     = (const float*)d_in[2];
    const float* logvar = (const float*)d_in[3];
    float* out = (float*)d_out;

    float*    partial = (float*)d_ws;                        // 32*65536 floats (8 MB)
    float*    sums    = partial + (size_t)CSPLIT * NSLOTS;   // 256 floats
    unsigned* counter = (unsigned*)(sums + 256);             // 1 uint

    dim3 g1(BLOCKS_X, CSPLIT);
    chamfer_stage1<<<g1, THREADS, 0, stream>>>(recon, x, partial, counter);
    chamfer_stage2<<<NSLOTS / THREADS, THREADS, 0, stream>>>(partial, mu, logvar,
                                                             sums, counter, out);
}